// Round 4
// baseline (337.728 us; speedup 1.0000x reference)
//
#include <hip/hip_runtime.h>
#include <math.h>

#define BB 8
#define FF 4096
#define DD 1024
#define HH 8
#define BF (BB * FF)   // 32768 rows

// ---------------------------------------------------------------------------
// K1: scoresT[h*BF + r] = sum_d |x[r][d]| * W[d][h] + b[h], f64 accumulation.
// ONE row per wave (32768 waves). All 4 x float4 loads issued upfront; W slice
// reloaded per j into a reused 32-reg buffer (sched_barrier stops hoisting).
// Reduction: fold heads across lane bits 5,4,3 then 3-step 8-lane reduce.
// ---------------------------------------------------------------------------
__global__ __launch_bounds__(256, 4) void k_scores(const float* __restrict__ x,
                                                   const float* __restrict__ W,
                                                   const float* __restrict__ b,
                                                   float* __restrict__ scoresT) {
    const int lane = threadIdx.x & 63;
    const int r    = (int)((blockIdx.x * blockDim.x + threadIdx.x) >> 6);

    // Issue all 4 x loads upfront (independent, in flight together).
    const float4* px = (const float4*)(x + (size_t)r * DD);
    float4 xv0 = px[lane];
    float4 xv1 = px[lane + 64];
    float4 xv2 = px[lane + 128];
    float4 xv3 = px[lane + 192];

    double acc[8];
#pragma unroll
    for (int h = 0; h < 8; ++h) acc[h] = 0.0;

#pragma unroll
    for (int j = 0; j < 4; ++j) {
        __builtin_amdgcn_sched_barrier(0);   // keep W loads inside their j-slot
        const int dbase = (lane + 64 * j) * 4;
        float wv[4][8];
#pragma unroll
        for (int c = 0; c < 4; ++c) {
            const float4* wp = (const float4*)(W + (size_t)(dbase + c) * HH);
            float4 w0 = wp[0], w1 = wp[1];
            wv[c][0] = w0.x; wv[c][1] = w0.y; wv[c][2] = w0.z; wv[c][3] = w0.w;
            wv[c][4] = w1.x; wv[c][5] = w1.y; wv[c][6] = w1.z; wv[c][7] = w1.w;
        }
        const float4 v = (j == 0) ? xv0 : (j == 1) ? xv1 : (j == 2) ? xv2 : xv3;
        const float m0 = fabsf(v.x), m1 = fabsf(v.y),
                    m2 = fabsf(v.z), m3 = fabsf(v.w);
#pragma unroll
        for (int h = 0; h < 8; ++h)
            acc[h] += (double)m0 * (double)wv[0][h]
                    + (double)m1 * (double)wv[1][h]
                    + (double)m2 * (double)wv[2][h]
                    + (double)m3 * (double)wv[3][h];
    }

    const int b5 = (lane >> 5) & 1, b4 = (lane >> 4) & 1, b3 = (lane >> 3) & 1;
    // fold xor32: keep heads [b5*4, b5*4+4)
    double t[4];
#pragma unroll
    for (int i = 0; i < 4; ++i) {
        double send = b5 ? acc[i] : acc[4 + i];
        double recv = __shfl_xor(send, 32, 64);
        t[i] = (b5 ? acc[4 + i] : acc[i]) + recv;
    }
    // fold xor16: keep 2
    double u[2];
#pragma unroll
    for (int i = 0; i < 2; ++i) {
        double send = b4 ? t[i] : t[2 + i];
        double recv = __shfl_xor(send, 16, 64);
        u[i] = (b4 ? t[2 + i] : t[i]) + recv;
    }
    // fold xor8: keep 1 → head h = lane>>3 on lanes 8h
    double s;
    {
        double send = b3 ? u[0] : u[1];
        double recv = __shfl_xor(send, 8, 64);
        s = (b3 ? u[1] : u[0]) + recv;
    }
    s += __shfl_xor(s, 4, 64);
    s += __shfl_xor(s, 2, 64);
    s += __shfl_xor(s, 1, 64);
    if ((lane & 7) == 0) {
        const int h = lane >> 3;
        scoresT[(size_t)h * BF + r] = (float)(s + (double)b[h]);
    }
}

// ---------------------------------------------------------------------------
// K2: per (b,h) exact top-k via 8-bit radix select. Per-wave histograms +
// wave-level shuffle scans (3 barriers/pass). Overwrites scoresT with maskT.
// ---------------------------------------------------------------------------
__global__ __launch_bounds__(256) void k_topk(float* scoresT,
                                              const float* __restrict__ soff) {
    const int blk  = blockIdx.x;      // b*H + h
    const int b    = blk >> 3;
    const int h    = blk & 7;
    const int tid  = threadIdx.x;
    const int lane = tid & 63;
    const int w    = tid >> 6;

    __shared__ unsigned int keys[FF];        // 16 KB
    __shared__ unsigned int hist4[4][256];   // 4 KB, per-wave histograms
    __shared__ unsigned int wsum[4];
    __shared__ unsigned int sh_digit, sh_rem;

    // k per head — mirror the reference's float64 path.
    double o  = (double)soff[h];
    double sp = 1.0 / (1.0 + exp(-o)) * 0.3 + 0.15;
    int k = (int)((double)FF * sp);
    if (k < 1) k = 1;

    const size_t base = (size_t)h * BF + (size_t)b * FF;

    // Coalesced load -> order-preserving keys; clear histograms.
    for (int i = 0; i < 16; ++i) {
        const int f = i * 256 + tid;
        const unsigned int u = __float_as_uint(scoresT[base + f]);
        keys[f] = (u & 0x80000000u) ? ~u : (u | 0x80000000u);
    }
#pragma unroll
    for (int q = 0; q < 4; ++q) hist4[q][tid] = 0u;
    __syncthreads();

    unsigned int remaining = (unsigned int)k;
    unsigned int prefix = 0, pmask = 0;
    for (int pass = 3; pass >= 0; --pass) {
        const int shift = pass * 8;
        for (int i = 0; i < 16; ++i) {
            const unsigned int key = keys[i * 256 + tid];
            if ((key & pmask) == prefix)
                atomicAdd(&hist4[w][(key >> shift) & 255u], 1u);
        }
        __syncthreads();                              // (1) hist ready
        // Suffix sum S[bin] via prefix scan over reversed bins.
        const int rbin = 255 - tid;
        const unsigned int c = hist4[0][rbin] + hist4[1][rbin] +
                               hist4[2][rbin] + hist4[3][rbin];
        unsigned int P = c;
#pragma unroll
        for (int o2 = 1; o2 < 64; o2 <<= 1) {
            const unsigned int tt = __shfl_up(P, o2, 64);
            if (lane >= o2) P += tt;
        }
        if (lane == 63) wsum[w] = P;
        __syncthreads();                              // (2) wave sums ready
        unsigned int off = 0;
#pragma unroll
        for (int w2 = 0; w2 < 4; ++w2) if (w2 < w) off += wsum[w2];
        P += off;                                     // P = S[rbin]
        // select: S[d] >= remaining && S[d+1] (= P - c) < remaining
        if (P >= remaining && (P - c) < remaining) {
            sh_digit = (unsigned int)rbin;
            sh_rem   = remaining - (P - c);
        }
#pragma unroll
        for (int q = 0; q < 4; ++q) hist4[q][tid] = 0u;   // clear for next pass
        __syncthreads();                              // (3) digit + clear ready
        prefix |= sh_digit << shift;
        pmask  |= 255u << shift;
        remaining = sh_rem;
    }
    // prefix = key of k-th largest; remaining = #equal keys kept (lowest f).

    // Stable rank of equal keys (thread owns consecutive f = tid*16..+16).
    unsigned int cnt = 0;
    for (int i = 0; i < 16; ++i) cnt += (keys[tid * 16 + i] == prefix);
    unsigned int inc = cnt;
#pragma unroll
    for (int o2 = 1; o2 < 64; o2 <<= 1) {
        const unsigned int tt = __shfl_up(inc, o2, 64);
        if (lane >= o2) inc += tt;
    }
    if (lane == 63) wsum[w] = inc;
    __syncthreads();
    unsigned int off = 0;
#pragma unroll
    for (int w2 = 0; w2 < 4; ++w2) if (w2 < w) off += wsum[w2];
    unsigned int rank = off + inc - cnt;              // exclusive prefix

    // Overwrite scoresT slice with the mask (maskT layout), float4 stores.
    float mbuf[16];
    for (int i = 0; i < 16; ++i) {
        const unsigned int key = keys[tid * 16 + i];
        float m = 0.0f;
        if (key > prefix) {
            m = 1.0f;
        } else if (key == prefix) {
            m = (rank < remaining) ? 1.0f : 0.0f;
            rank++;
        }
        mbuf[i] = m;
    }
    float4* dst = (float4*)(scoresT + base + (size_t)tid * 16);
#pragma unroll
    for (int q = 0; q < 4; ++q)
        dst[q] = make_float4(mbuf[q * 4], mbuf[q * 4 + 1],
                             mbuf[q * 4 + 2], mbuf[q * 4 + 3]);
}

// ---------------------------------------------------------------------------
// K3: out_x = mask ? x : 0 — skips the x read where mask==0 (saves ~70% of
// the x re-read). Also emits out_mask in (B,F,H) layout.
// ---------------------------------------------------------------------------
__global__ __launch_bounds__(256) void k_filter(const float* __restrict__ x,
                                                const float* __restrict__ maskT,
                                                float* __restrict__ out_x,
                                                float* __restrict__ out_mask) {
    const size_t stride = (size_t)gridDim.x * blockDim.x;   // 2,097,152
    const size_t i0 = (size_t)blockIdx.x * blockDim.x + threadIdx.x;
    const float4* x4 = (const float4*)x;
    float4* o4 = (float4*)out_x;
#pragma unroll
    for (int it = 0; it < 4; ++it) {
        const size_t i = i0 + (size_t)it * stride;
        const size_t r = i >> 8;                        // row b*F+f
        const unsigned int j = (unsigned int)i & 255u;
        const unsigned int h = j >> 5;                  // 32 float4 per head
        const float mv = maskT[(size_t)h * BF + r];
        float4 v = make_float4(0.f, 0.f, 0.f, 0.f);
        if (mv != 0.0f) v = x4[i];                      // exec-masked load
        o4[i] = v;
        if (j < 8)
            out_mask[r * HH + j] = maskT[(size_t)j * BF + r];
    }
}

extern "C" void kernel_launch(void* const* d_in, const int* in_sizes, int n_in,
                              void* d_out, int out_size, void* d_ws, size_t ws_size,
                              hipStream_t stream) {
    const float* x  = (const float*)d_in[0];   // (B,F,D)
    const float* W  = (const float*)d_in[1];   // (D,H)
    const float* bi = (const float*)d_in[2];   // (H,)
    const float* so = (const float*)d_in[3];   // (H,)

    float* out_x    = (float*)d_out;                         // B*F*D
    float* out_mask = (float*)d_out + (size_t)BB * FF * DD;  // B*F*H
    float* scoresT  = (float*)d_ws;                          // [H][BF] floats (1 MB)

    k_scores<<<8192, 256, 0, stream>>>(x, W, bi, scoresT);   // 1 row per wave
    k_topk<<<BB * HH, 256, 0, stream>>>(scoresT, so);
    k_filter<<<8192, 256, 0, stream>>>(x, scoresT, out_x, out_mask);
}

// Round 5
// 259.184 us; speedup vs baseline: 1.3030x; 1.3030x over previous
//
#include <hip/hip_runtime.h>
#include <math.h>

#define BB 8
#define FF 4096
#define DD 1024
#define HH 8
#define BF (BB * FF)   // 32768 rows

// ---------------------------------------------------------------------------
// K1: scoresT[h*BF + r] = sum_d |x[r][d]| * W[d][h] + b[h], f64 accumulation.
// Block (4 waves) owns 16 rows. Wave w owns d-chunk [256w, 256w+256): lane l
// owns d = 256w + 4l + c. W slice = 128 contiguous B/lane, loaded ONCE.
// All 16 row-loads issued upfront. Per row: 32 f64 FMA + 6-level fold
// (verified mapping) -> f64 partial to LDS -> cross-wave sum -> store.
// ---------------------------------------------------------------------------
__global__ __launch_bounds__(256) void k_scores(const float* __restrict__ x,
                                                const float* __restrict__ W,
                                                const float* __restrict__ b,
                                                float* __restrict__ scoresT) {
    const int tid  = threadIdx.x;
    const int lane = tid & 63;
    const int w    = tid >> 6;            // wave 0..3 = d-chunk
    const int r0   = blockIdx.x * 16;

    __shared__ double partial[16 * 36];   // idx row*36 + w*9 + h (padded)

    // W for this lane: d = w*256 + 4l + c -> float4 idx w*512 + 8l + 2c (+1)
    const float4* W4 = (const float4*)W;
    const int wb = w * 512 + lane * 8;
    float wv[4][8];
#pragma unroll
    for (int c = 0; c < 4; ++c) {
        const float4 q0 = W4[wb + 2 * c];
        const float4 q1 = W4[wb + 2 * c + 1];
        wv[c][0] = q0.x; wv[c][1] = q0.y; wv[c][2] = q0.z; wv[c][3] = q0.w;
        wv[c][4] = q1.x; wv[c][5] = q1.y; wv[c][6] = q1.z; wv[c][7] = q1.w;
    }

    // All 16 rows' x loads upfront (coalesced 1KB/instr, all in flight).
    const float4* x4 = (const float4*)x;
    float4 xv[16];
#pragma unroll
    for (int rr = 0; rr < 16; ++rr)
        xv[rr] = x4[(size_t)(r0 + rr) * 256 + w * 64 + lane];

    const int b5 = (lane >> 5) & 1, b4 = (lane >> 4) & 1, b3 = (lane >> 3) & 1;

#pragma unroll
    for (int rr = 0; rr < 16; ++rr) {
        const float4 v = xv[rr];
        const float m0 = fabsf(v.x), m1 = fabsf(v.y),
                    m2 = fabsf(v.z), m3 = fabsf(v.w);
        double acc[8];
#pragma unroll
        for (int h = 0; h < 8; ++h)
            acc[h] = (double)m0 * (double)wv[0][h]
                   + (double)m1 * (double)wv[1][h]
                   + (double)m2 * (double)wv[2][h]
                   + (double)m3 * (double)wv[3][h];

        // fold xor32: keep heads [b5*4, b5*4+4)
        double t[4];
#pragma unroll
        for (int i = 0; i < 4; ++i) {
            double send = b5 ? acc[i] : acc[4 + i];
            double recv = __shfl_xor(send, 32, 64);
            t[i] = (b5 ? acc[4 + i] : acc[i]) + recv;
        }
        // fold xor16: keep 2
        double u[2];
#pragma unroll
        for (int i = 0; i < 2; ++i) {
            double send = b4 ? t[i] : t[2 + i];
            double recv = __shfl_xor(send, 16, 64);
            u[i] = (b4 ? t[2 + i] : t[i]) + recv;
        }
        // fold xor8: keep 1 -> head h = lane>>3 on lanes with (lane&7)==0
        double s;
        {
            double send = b3 ? u[0] : u[1];
            double recv = __shfl_xor(send, 8, 64);
            s = (b3 ? u[1] : u[0]) + recv;
        }
        s += __shfl_xor(s, 4, 64);
        s += __shfl_xor(s, 2, 64);
        s += __shfl_xor(s, 1, 64);
        if ((lane & 7) == 0)
            partial[rr * 36 + w * 9 + (lane >> 3)] = s;
    }
    __syncthreads();

    if (tid < 128) {
        const int row = tid & 15, hh = tid >> 4;
        const double s = partial[row * 36 + 0 + hh] + partial[row * 36 + 9 + hh]
                       + partial[row * 36 + 18 + hh] + partial[row * 36 + 27 + hh];
        scoresT[(size_t)hh * BF + (r0 + row)] = (float)(s + (double)b[hh]);
    }
}

// ---------------------------------------------------------------------------
// K2: per (b,h) exact top-k via 8-bit radix select, 512 threads / 8 waves.
// High-byte pass over all keys, then survivor-index compaction (fallback to
// full scans if >1024 survivors); passes 2-4 iterate the tiny list.
// Overwrites scoresT slice in place with maskT.
// ---------------------------------------------------------------------------
__global__ __launch_bounds__(512) void k_topk(float* scoresT,
                                              const float* __restrict__ soff) {
    const int blk  = blockIdx.x;      // b*H + h
    const int bb   = blk >> 3;
    const int h    = blk & 7;
    const int tid  = threadIdx.x;
    const int lane = tid & 63;
    const int w    = tid >> 6;        // 8 waves

    __shared__ unsigned int keys[FF];        // 16 KB
    __shared__ unsigned int hist8[8][256];   // 8 KB
    __shared__ unsigned int wsum[8];
    __shared__ unsigned int idxlist[1024];
    __shared__ unsigned int sh_digit, sh_rem, sh_cnt, sh_n;

    // k per head — mirror the reference's float64 path.
    double o  = (double)soff[h];
    double sp = 1.0 / (1.0 + exp(-o)) * 0.3 + 0.15;
    int k = (int)((double)FF * sp);
    if (k < 1) k = 1;

    const size_t base = (size_t)h * BF + (size_t)bb * FF;

    for (int i = 0; i < 8; ++i) {
        const int f = i * 512 + tid;
        const unsigned int u = __float_as_uint(scoresT[base + f]);
        keys[f] = (u & 0x80000000u) ? ~u : (u | 0x80000000u);
    }
    for (int q = 0; q < 4; ++q) ((unsigned int*)hist8)[q * 512 + tid] = 0u;
    if (tid == 0) sh_n = 0u;
    __syncthreads();

    // ---- pass 1: high byte over all keys
    for (int i = 0; i < 8; ++i)
        atomicAdd(&hist8[w][keys[i * 512 + tid] >> 24], 1u);
    __syncthreads();

    unsigned int remaining = (unsigned int)k;
    {
        unsigned int P = 0, c = 0;
        if (tid < 256) {
            const int rbin = 255 - tid;
#pragma unroll
            for (int q = 0; q < 8; ++q) c += hist8[q][rbin];
            P = c;
#pragma unroll
            for (int o2 = 1; o2 < 64; o2 <<= 1) {
                const unsigned int t2 = __shfl_up(P, o2, 64);
                if (lane >= o2) P += t2;
            }
            if (lane == 63) wsum[w] = P;
        }
        __syncthreads();
        if (tid < 256) {
            unsigned int off = 0;
#pragma unroll
            for (int w2 = 0; w2 < 4; ++w2) if (w2 < w) off += wsum[w2];
            P += off;
            if (P >= remaining && (P - c) < remaining) {
                sh_digit = (unsigned int)(255 - tid);
                sh_rem   = remaining - (P - c);
                sh_cnt   = c;
            }
        }
        __syncthreads();
    }
    unsigned int prefix = sh_digit << 24;
    unsigned int pmask  = 0xFF000000u;
    remaining = sh_rem;
    const bool compact = (sh_cnt <= 1024u);

    // clear hists; build survivor list
    for (int q = 0; q < 4; ++q) ((unsigned int*)hist8)[q * 512 + tid] = 0u;
    if (compact) {
        for (int i = 0; i < 8; ++i) {
            const int f = i * 512 + tid;
            if ((keys[f] & pmask) == prefix) {
                const unsigned int pos = atomicAdd(&sh_n, 1u);
                idxlist[pos] = (unsigned int)f;
            }
        }
    }
    __syncthreads();
    const int n = compact ? (int)sh_n : FF;

    for (int pass = 2; pass >= 0; --pass) {
        const int shift = pass * 8;
        if (compact) {
            for (int i = tid; i < n; i += 512) {
                const unsigned int key = keys[idxlist[i]];
                if ((key & pmask) == prefix)
                    atomicAdd(&hist8[w][(key >> shift) & 255u], 1u);
            }
        } else {
            for (int i = 0; i < 8; ++i) {
                const unsigned int key = keys[i * 512 + tid];
                if ((key & pmask) == prefix)
                    atomicAdd(&hist8[w][(key >> shift) & 255u], 1u);
            }
        }
        __syncthreads();
        unsigned int P = 0, c = 0;
        if (tid < 256) {
            const int rbin = 255 - tid;
#pragma unroll
            for (int q = 0; q < 8; ++q) c += hist8[q][rbin];
            P = c;
#pragma unroll
            for (int o2 = 1; o2 < 64; o2 <<= 1) {
                const unsigned int t2 = __shfl_up(P, o2, 64);
                if (lane >= o2) P += t2;
            }
            if (lane == 63) wsum[w] = P;
        }
        __syncthreads();
        if (tid < 256) {
            unsigned int off = 0;
#pragma unroll
            for (int w2 = 0; w2 < 4; ++w2) if (w2 < w) off += wsum[w2];
            P += off;
            if (P >= remaining && (P - c) < remaining) {
                sh_digit = (unsigned int)(255 - tid);
                sh_rem   = remaining - (P - c);
            }
        }
        __syncthreads();
        for (int q = 0; q < 4; ++q) ((unsigned int*)hist8)[q * 512 + tid] = 0u;
        prefix |= sh_digit << shift;
        pmask  |= 255u << shift;
        remaining = sh_rem;
        __syncthreads();
    }
    // prefix = exact key of k-th largest; remaining = #equal keys kept.

    // Stable rank of equal keys (thread owns consecutive f = tid*8..+8).
    unsigned int cnt = 0;
#pragma unroll
    for (int i = 0; i < 8; ++i) cnt += (keys[tid * 8 + i] == prefix);
    unsigned int inc = cnt;
#pragma unroll
    for (int o2 = 1; o2 < 64; o2 <<= 1) {
        const unsigned int t2 = __shfl_up(inc, o2, 64);
        if (lane >= o2) inc += t2;
    }
    if (lane == 63) wsum[w] = inc;
    __syncthreads();
    unsigned int off2 = 0;
#pragma unroll
    for (int w2 = 0; w2 < 8; ++w2) if (w2 < w) off2 += wsum[w2];
    unsigned int rank = off2 + inc - cnt;

    float mbuf[8];
#pragma unroll
    for (int i = 0; i < 8; ++i) {
        const unsigned int key = keys[tid * 8 + i];
        float m = 0.0f;
        if (key > prefix) {
            m = 1.0f;
        } else if (key == prefix) {
            m = (rank < remaining) ? 1.0f : 0.0f;
            rank++;
        }
        mbuf[i] = m;
    }
    float4* dst = (float4*)(scoresT + base + (size_t)tid * 8);
    dst[0] = make_float4(mbuf[0], mbuf[1], mbuf[2], mbuf[3]);
    dst[1] = make_float4(mbuf[4], mbuf[5], mbuf[6], mbuf[7]);
}

// ---------------------------------------------------------------------------
// K3: out_x = mask ? x : 0 (skips x read where mask==0); emits out_mask.
// ---------------------------------------------------------------------------
__global__ __launch_bounds__(256) void k_filter(const float* __restrict__ x,
                                                const float* __restrict__ maskT,
                                                float* __restrict__ out_x,
                                                float* __restrict__ out_mask) {
    const size_t stride = (size_t)gridDim.x * blockDim.x;   // 2,097,152
    const size_t i0 = (size_t)blockIdx.x * blockDim.x + threadIdx.x;
    const float4* x4 = (const float4*)x;
    float4* o4 = (float4*)out_x;
#pragma unroll
    for (int it = 0; it < 4; ++it) {
        const size_t i = i0 + (size_t)it * stride;
        const size_t r = i >> 8;                        // row b*F+f
        const unsigned int j = (unsigned int)i & 255u;
        const unsigned int h = j >> 5;                  // 32 float4 per head
        const float mv = maskT[(size_t)h * BF + r];
        float4 v = make_float4(0.f, 0.f, 0.f, 0.f);
        if (mv != 0.0f) v = x4[i];                      // exec-masked load
        o4[i] = v;
        if (j < 8)
            out_mask[r * HH + j] = maskT[(size_t)j * BF + r];
    }
}

extern "C" void kernel_launch(void* const* d_in, const int* in_sizes, int n_in,
                              void* d_out, int out_size, void* d_ws, size_t ws_size,
                              hipStream_t stream) {
    const float* x  = (const float*)d_in[0];   // (B,F,D)
    const float* W  = (const float*)d_in[1];   // (D,H)
    const float* bi = (const float*)d_in[2];   // (H,)
    const float* so = (const float*)d_in[3];   // (H,)

    float* out_x    = (float*)d_out;                         // B*F*D
    float* out_mask = (float*)d_out + (size_t)BB * FF * DD;  // B*F*H
    float* scoresT  = (float*)d_ws;                          // [H][BF] floats (1 MB)

    k_scores<<<2048, 256, 0, stream>>>(x, W, bi, scoresT);   // 16 rows/block
    k_topk<<<BB * HH, 512, 0, stream>>>(scoresT, so);
    k_filter<<<8192, 256, 0, stream>>>(x, scoresT, out_x, out_mask);
}

// Round 6
// 255.357 us; speedup vs baseline: 1.3226x; 1.0150x over previous
//
#include <hip/hip_runtime.h>
#include <math.h>

#define BB 8
#define FF 4096
#define DD 1024
#define HH 8
#define BF (BB * FF)   // 32768 rows

// ---------------------------------------------------------------------------
// K1: scoresT[h*BF + r] = sum_d |x[r][d]| * W[d][h] + b[h], f64 accumulation.
// Block (4 waves) owns 8 rows. Wave w owns d-chunk [256w, 256w+256): lane l
// owns d = 256w + 4l + c. W slice = 128 contiguous B/lane, loaded ONCE.
// All 8 row-loads issued upfront (32 VGPRs). Per row: 32 f64 FMA + 6-level
// fold (verified) -> f64 partial to LDS -> cross-wave sum -> store.
// ---------------------------------------------------------------------------
__global__ __launch_bounds__(256) void k_scores(const float* __restrict__ x,
                                                const float* __restrict__ W,
                                                const float* __restrict__ b,
                                                float* __restrict__ scoresT) {
    const int tid  = threadIdx.x;
    const int lane = tid & 63;
    const int w    = tid >> 6;            // wave 0..3 = d-chunk
    const int r0   = blockIdx.x * 8;

    __shared__ double partial[8 * 36];    // idx row*36 + w*9 + h (padded)

    // W for this lane: d = w*256 + 4l + c -> float4 idx w*512 + 8l + 2c (+1)
    const float4* W4 = (const float4*)W;
    const int wb = w * 512 + lane * 8;
    float wv[4][8];
#pragma unroll
    for (int c = 0; c < 4; ++c) {
        const float4 q0 = W4[wb + 2 * c];
        const float4 q1 = W4[wb + 2 * c + 1];
        wv[c][0] = q0.x; wv[c][1] = q0.y; wv[c][2] = q0.z; wv[c][3] = q0.w;
        wv[c][4] = q1.x; wv[c][5] = q1.y; wv[c][6] = q1.z; wv[c][7] = q1.w;
    }

    // All 8 rows' x loads upfront (coalesced 1KB/instr, all in flight).
    const float4* x4 = (const float4*)x;
    float4 xv[8];
#pragma unroll
    for (int rr = 0; rr < 8; ++rr)
        xv[rr] = x4[(size_t)(r0 + rr) * 256 + w * 64 + lane];

    const int b5 = (lane >> 5) & 1, b4 = (lane >> 4) & 1, b3 = (lane >> 3) & 1;

#pragma unroll
    for (int rr = 0; rr < 8; ++rr) {
        const float4 v = xv[rr];
        const float m0 = fabsf(v.x), m1 = fabsf(v.y),
                    m2 = fabsf(v.z), m3 = fabsf(v.w);
        double acc[8];
#pragma unroll
        for (int h = 0; h < 8; ++h)
            acc[h] = (double)m0 * (double)wv[0][h]
                   + (double)m1 * (double)wv[1][h]
                   + (double)m2 * (double)wv[2][h]
                   + (double)m3 * (double)wv[3][h];

        // fold xor32: keep heads [b5*4, b5*4+4)
        double t[4];
#pragma unroll
        for (int i = 0; i < 4; ++i) {
            double send = b5 ? acc[i] : acc[4 + i];
            double recv = __shfl_xor(send, 32, 64);
            t[i] = (b5 ? acc[4 + i] : acc[i]) + recv;
        }
        // fold xor16: keep 2
        double u[2];
#pragma unroll
        for (int i = 0; i < 2; ++i) {
            double send = b4 ? t[i] : t[2 + i];
            double recv = __shfl_xor(send, 16, 64);
            u[i] = (b4 ? t[2 + i] : t[i]) + recv;
        }
        // fold xor8: keep 1 -> head h = lane>>3 on lanes with (lane&7)==0
        double s;
        {
            double send = b3 ? u[0] : u[1];
            double recv = __shfl_xor(send, 8, 64);
            s = (b3 ? u[1] : u[0]) + recv;
        }
        s += __shfl_xor(s, 4, 64);
        s += __shfl_xor(s, 2, 64);
        s += __shfl_xor(s, 1, 64);
        if ((lane & 7) == 0)
            partial[rr * 36 + w * 9 + (lane >> 3)] = s;
    }
    __syncthreads();

    if (tid < 64) {
        const int row = tid & 7, hh = tid >> 3;
        const double s = partial[row * 36 + 0 + hh] + partial[row * 36 + 9 + hh]
                       + partial[row * 36 + 18 + hh] + partial[row * 36 + 27 + hh];
        scoresT[(size_t)hh * BF + (r0 + row)] = (float)(s + (double)b[hh]);
    }
}

// ---------------------------------------------------------------------------
// K2: per (b,h) exact top-k via 8-bit radix select, 512 threads / 8 waves.
// High-byte pass over all keys, then survivor-index compaction (<=2048,
// fallback to full scans otherwise). Overwrites scoresT slice with maskT
// AND writes out_mask in (B,F,H) layout.
// ---------------------------------------------------------------------------
__global__ __launch_bounds__(512) void k_topk(float* scoresT,
                                              const float* __restrict__ soff,
                                              float* __restrict__ out_mask) {
    const int blk  = blockIdx.x;      // b*H + h
    const int bb   = blk >> 3;
    const int h    = blk & 7;
    const int tid  = threadIdx.x;
    const int lane = tid & 63;
    const int w    = tid >> 6;        // 8 waves

    __shared__ unsigned int keys[FF];        // 16 KB
    __shared__ unsigned int hist8[8][256];   // 8 KB
    __shared__ unsigned int wsum[8];
    __shared__ unsigned int idxlist[2048];   // 8 KB
    __shared__ unsigned int sh_digit, sh_rem, sh_cnt, sh_n;

    // k per head — mirror the reference's float64 path.
    double o  = (double)soff[h];
    double sp = 1.0 / (1.0 + exp(-o)) * 0.3 + 0.15;
    int k = (int)((double)FF * sp);
    if (k < 1) k = 1;

    const size_t base = (size_t)h * BF + (size_t)bb * FF;

    for (int i = 0; i < 8; ++i) {
        const int f = i * 512 + tid;
        const unsigned int u = __float_as_uint(scoresT[base + f]);
        keys[f] = (u & 0x80000000u) ? ~u : (u | 0x80000000u);
    }
    for (int q = 0; q < 4; ++q) ((unsigned int*)hist8)[q * 512 + tid] = 0u;
    if (tid == 0) sh_n = 0u;
    __syncthreads();

    // ---- pass 1: high byte over all keys
    for (int i = 0; i < 8; ++i)
        atomicAdd(&hist8[w][keys[i * 512 + tid] >> 24], 1u);
    __syncthreads();

    unsigned int remaining = (unsigned int)k;
    {
        unsigned int P = 0, c = 0;
        if (tid < 256) {
            const int rbin = 255 - tid;
#pragma unroll
            for (int q = 0; q < 8; ++q) c += hist8[q][rbin];
            P = c;
#pragma unroll
            for (int o2 = 1; o2 < 64; o2 <<= 1) {
                const unsigned int t2 = __shfl_up(P, o2, 64);
                if (lane >= o2) P += t2;
            }
            if (lane == 63) wsum[w] = P;
        }
        __syncthreads();
        if (tid < 256) {
            unsigned int off = 0;
#pragma unroll
            for (int w2 = 0; w2 < 4; ++w2) if (w2 < w) off += wsum[w2];
            P += off;
            if (P >= remaining && (P - c) < remaining) {
                sh_digit = (unsigned int)(255 - tid);
                sh_rem   = remaining - (P - c);
                sh_cnt   = c;
            }
        }
        __syncthreads();
    }
    unsigned int prefix = sh_digit << 24;
    unsigned int pmask  = 0xFF000000u;
    remaining = sh_rem;
    const bool compact = (sh_cnt <= 2048u);

    // clear hists; build survivor list
    for (int q = 0; q < 4; ++q) ((unsigned int*)hist8)[q * 512 + tid] = 0u;
    if (compact) {
        for (int i = 0; i < 8; ++i) {
            const int f = i * 512 + tid;
            if ((keys[f] & pmask) == prefix) {
                const unsigned int pos = atomicAdd(&sh_n, 1u);
                idxlist[pos] = (unsigned int)f;
            }
        }
    }
    __syncthreads();
    const int n = compact ? (int)sh_n : FF;

    for (int pass = 2; pass >= 0; --pass) {
        const int shift = pass * 8;
        if (compact) {
            for (int i = tid; i < n; i += 512) {
                const unsigned int key = keys[idxlist[i]];
                if ((key & pmask) == prefix)
                    atomicAdd(&hist8[w][(key >> shift) & 255u], 1u);
            }
        } else {
            for (int i = 0; i < 8; ++i) {
                const unsigned int key = keys[i * 512 + tid];
                if ((key & pmask) == prefix)
                    atomicAdd(&hist8[w][(key >> shift) & 255u], 1u);
            }
        }
        __syncthreads();
        unsigned int P = 0, c = 0;
        if (tid < 256) {
            const int rbin = 255 - tid;
#pragma unroll
            for (int q = 0; q < 8; ++q) c += hist8[q][rbin];
            P = c;
#pragma unroll
            for (int o2 = 1; o2 < 64; o2 <<= 1) {
                const unsigned int t2 = __shfl_up(P, o2, 64);
                if (lane >= o2) P += t2;
            }
            if (lane == 63) wsum[w] = P;
        }
        __syncthreads();
        if (tid < 256) {
            unsigned int off = 0;
#pragma unroll
            for (int w2 = 0; w2 < 4; ++w2) if (w2 < w) off += wsum[w2];
            P += off;
            if (P >= remaining && (P - c) < remaining) {
                sh_digit = (unsigned int)(255 - tid);
                sh_rem   = remaining - (P - c);
            }
        }
        __syncthreads();
        for (int q = 0; q < 4; ++q) ((unsigned int*)hist8)[q * 512 + tid] = 0u;
        prefix |= sh_digit << shift;
        pmask  |= 255u << shift;
        remaining = sh_rem;
        __syncthreads();
    }
    // prefix = exact key of k-th largest; remaining = #equal keys kept.

    // Stable rank of equal keys (thread owns consecutive f = tid*8..+8).
    unsigned int cnt = 0;
#pragma unroll
    for (int i = 0; i < 8; ++i) cnt += (keys[tid * 8 + i] == prefix);
    unsigned int inc = cnt;
#pragma unroll
    for (int o2 = 1; o2 < 64; o2 <<= 1) {
        const unsigned int t2 = __shfl_up(inc, o2, 64);
        if (lane >= o2) inc += t2;
    }
    if (lane == 63) wsum[w] = inc;
    __syncthreads();
    unsigned int off2 = 0;
#pragma unroll
    for (int w2 = 0; w2 < 8; ++w2) if (w2 < w) off2 += wsum[w2];
    unsigned int rank = off2 + inc - cnt;

    float mbuf[8];
#pragma unroll
    for (int i = 0; i < 8; ++i) {
        const unsigned int key = keys[tid * 8 + i];
        float m = 0.0f;
        if (key > prefix) {
            m = 1.0f;
        } else if (key == prefix) {
            m = (rank < remaining) ? 1.0f : 0.0f;
            rank++;
        }
        mbuf[i] = m;
    }
    float4* dst = (float4*)(scoresT + base + (size_t)tid * 8);
    dst[0] = make_float4(mbuf[0], mbuf[1], mbuf[2], mbuf[3]);
    dst[1] = make_float4(mbuf[4], mbuf[5], mbuf[6], mbuf[7]);
    // out_mask in (B,F,H) layout: thread owns f = tid*8..+8 for head h.
    float* om = out_mask + ((size_t)bb * FF + (size_t)tid * 8) * HH + h;
#pragma unroll
    for (int i = 0; i < 8; ++i) om[i * HH] = mbuf[i];
}

// ---------------------------------------------------------------------------
// K3: out_x = mask ? x : 0 (skips x read where mask==0). Pure stream.
// ---------------------------------------------------------------------------
__global__ __launch_bounds__(256) void k_filter(const float* __restrict__ x,
                                                const float* __restrict__ maskT,
                                                float* __restrict__ out_x) {
    const size_t stride = (size_t)gridDim.x * blockDim.x;   // 2,097,152
    const size_t i0 = (size_t)blockIdx.x * blockDim.x + threadIdx.x;
    const float4* x4 = (const float4*)x;
    float4* o4 = (float4*)out_x;
#pragma unroll
    for (int it = 0; it < 4; ++it) {
        const size_t i = i0 + (size_t)it * stride;
        const size_t r = i >> 8;                        // row b*F+f
        const unsigned int j = (unsigned int)i & 255u;
        const unsigned int h = j >> 5;                  // 32 float4 per head
        const float mv = maskT[(size_t)h * BF + r];
        float4 v = make_float4(0.f, 0.f, 0.f, 0.f);
        if (mv != 0.0f) v = x4[i];                      // exec-masked load
        o4[i] = v;
    }
}

extern "C" void kernel_launch(void* const* d_in, const int* in_sizes, int n_in,
                              void* d_out, int out_size, void* d_ws, size_t ws_size,
                              hipStream_t stream) {
    const float* x  = (const float*)d_in[0];   // (B,F,D)
    const float* W  = (const float*)d_in[1];   // (D,H)
    const float* bi = (const float*)d_in[2];   // (H,)
    const float* so = (const float*)d_in[3];   // (H,)

    float* out_x    = (float*)d_out;                         // B*F*D
    float* out_mask = (float*)d_out + (size_t)BB * FF * DD;  // B*F*H
    float* scoresT  = (float*)d_ws;                          // [H][BF] floats (1 MB)

    k_scores<<<4096, 256, 0, stream>>>(x, W, bi, scoresT);   // 8 rows/block
    k_topk<<<BB * HH, 512, 0, stream>>>(scoresT, so, out_mask);
    k_filter<<<8192, 256, 0, stream>>>(x, scoresT, out_x);
}